// Round 6
// baseline (523.442 us; speedup 1.0000x reference)
//
#include <hip/hip_runtime.h>
#include <hip/hip_cooperative_groups.h>
namespace cg = cooperative_groups;

#define NN 50000
#define DD 128
#define SLOPE 0.01f
#define NB 782        // buckets of 64 nodes: bucket = v>>6
#define BCAP 2304     // per-bucket cap; mean 2046, sigma 45 -> +5.7 sigma (+ovf net)
#define ECH 3072      // edges per chunk (521 chunks -> 2 blocks/CU, was 1.02)
#define BST 512       // binning block threads
#define PB 2          // buckets per thread in prefix scan (512*2 >= 782)
#define OVCAP 8192
#define HP 136        // Hs row pitch (bf16): 272B rows -> even b128 bank groups

using bf16x8 = __attribute__((ext_vector_type(8))) short;
using f32x4  = __attribute__((ext_vector_type(4))) float;

// ---------------- bf16 helpers (RNE) ----------------
__device__ inline float bflo(unsigned int w) { return __uint_as_float(w << 16); }
__device__ inline float bfhi(unsigned int w) { return __uint_as_float(w & 0xffff0000u); }
__device__ inline float sbf(short s) {
    return __uint_as_float(((unsigned int)(unsigned short)s) << 16);
}
__device__ inline unsigned int rnebf(float f) {
    unsigned int u = __float_as_uint(f);
    return (u + 0x7fffu + ((u >> 16) & 1u)) >> 16;
}
__device__ inline unsigned int pack2(float lo, float hi) {
    return rnebf(lo) | (rnebf(hi) << 16);
}

// Ebf is stored as 4 COLUMN PLANES: plane q holds dwords [q*16, q*16+16) of
// every row (= bf16 cols [q*32, q*32+32)), contiguously: plane = 3.2 MB.
// Rationale [r5 counters]: FETCH_SIZE pinned at 146 MB across all gather
// structures -> L2-miss bound (Ebf 12.8 MB > 4 MB per-XCD L2). A 3.2 MB
// plane FITS, so a per-plane gather pass runs ~all-L2-hit.
__device__ inline void convert_item(
    const float* __restrict__ E, const float* __restrict__ W1,
    const float* __restrict__ W2, unsigned short* __restrict__ Ebf,
    unsigned short* __restrict__ W1b, unsigned short* __restrict__ W2b, int t)
{
    const int NE8 = NN * DD / 8;      // 800000
    const int NW8 = DD * DD / 8;      // 2048
    const float* s; unsigned short* d; size_t oidx;
    if (t < NE8) {
        s = E;
        int r = t >> 4, sl = t & 15;          // row, 8-col slot
        int p = sl >> 2, q4 = sl & 3;          // plane, uint4 within plane row
        oidx = ((size_t)p * NN + r) * 4 + q4;  // plane-major uint4 index
        d = Ebf;
        float4 a = ((const float4*)s)[(size_t)t * 2];
        float4 b = ((const float4*)s)[(size_t)t * 2 + 1];
        uint4 o;
        o.x = pack2(a.x, a.y); o.y = pack2(a.z, a.w);
        o.z = pack2(b.x, b.y); o.w = pack2(b.z, b.w);
        ((uint4*)d)[oidx] = o;
        return;
    }
    int idx;
    if (t < NE8 + NW8)          { s = W1; d = W1b; idx = t - NE8; }
    else if (t < NE8 + 2 * NW8) { s = W2; d = W2b; idx = t - NE8 - NW8; }
    else return;
    float4 a = ((const float4*)s)[(size_t)idx * 2];
    float4 b = ((const float4*)s)[(size_t)idx * 2 + 1];
    uint4 o;
    o.x = pack2(a.x, a.y); o.y = pack2(a.z, a.w);
    o.z = pack2(b.x, b.y); o.w = pack2(b.z, b.w);
    ((uint4*)d)[idx] = o;
}

// ---------------------------------------------------------------------------
// Cooperative single-kernel binning (one dispatch -> finally gets its own
// rocprof row; r0-r4 showed binning ~107us total but never surfaced in top-5).
//   phase1: count my ECH chunk into LDS cnt[NB] -> cnt_g[bb][blk];
//           grid-stride fp32->bf16 convert fills idle time.
//   grid.sync
//   phase2: wave gw<NB scans cnt_g[gw][*] in place -> exclusive bases, gtail.
//   grid.sync
//   phase3: reuse LDS cnt[] (no re-histogram!): local scan -> off/pos,
//           LDS counting sort -> srt, deterministic flush to stag.
// ---------------------------------------------------------------------------
__global__ __launch_bounds__(BST) void bin_coop(
    const float* __restrict__ E, const float* __restrict__ W1,
    const float* __restrict__ W2, const int* __restrict__ src,
    const int* __restrict__ dst, unsigned short* __restrict__ Ebf,
    unsigned short* __restrict__ W1b, unsigned short* __restrict__ W2b,
    int* __restrict__ cnt_g, int* __restrict__ gtail,
    unsigned int* __restrict__ stag, int* __restrict__ ovf_cnt,
    int2* __restrict__ ovf, int n_edges, int nchunk)
{
    __shared__ unsigned int srt[ECH];     // 12 KB
    __shared__ int cnt[NB], off[NB], pos[NB], gbase[NB];
    __shared__ int wsum[BST / 64];

    const int tid = threadIdx.x;
    const int blk = blockIdx.x;
    const int e0 = blk * ECH;
    const int m = min(ECH, n_edges - e0);

    // ---- phase 1: count + convert ----
    for (int b = tid; b < NB; b += BST) cnt[b] = 0;
    __syncthreads();
    for (int i = tid; i < m; i += BST)
        atomicAdd(&cnt[dst[e0 + i] >> 6], 1);
    __syncthreads();
    for (int b = tid; b < NB; b += BST)
        cnt_g[(size_t)b * nchunk + blk] = cnt[b];

    const int NCV = NN * DD / 8 + 2 * (DD * DD / 8);
    for (int t = blk * BST + tid; t < NCV; t += gridDim.x * BST)
        convert_item(E, W1, W2, Ebf, W1b, W2b, t);

    __threadfence();
    cg::this_grid().sync();

    // ---- phase 2: per-bucket scan across chunks ----
    {
        const int gw = blk * (BST / 64) + (tid >> 6);
        const int lane = tid & 63;
        if (gw == 0 && lane == 0) *ovf_cnt = 0;
        if (gw < NB) {
            int* row = cnt_g + (size_t)gw * nchunk;
            int carry = 0;
            for (int base = 0; base < nchunk; base += 64) {
                int c = base + lane;
                int v = (c < nchunk) ? row[c] : 0;
                int incl = v;
                #pragma unroll
                for (int d = 1; d < 64; d <<= 1) {
                    int t2 = __shfl_up(incl, d);
                    if (lane >= d) incl += t2;
                }
                if (c < nchunk) row[c] = carry + incl - v;   // exclusive base
                carry += __shfl(incl, 63);
            }
            if (lane == 0) gtail[gw] = carry;
        }
    }
    __threadfence();
    cg::this_grid().sync();

    // ---- phase 3: sort + flush (cnt[] still live in LDS) ----
    for (int b = tid; b < NB; b += BST)
        gbase[b] = cnt_g[(size_t)b * nchunk + blk];

    const int lane = tid & 63, w = tid >> 6;
    int b0 = tid * PB;
    int loc[PB]; int s = 0;
    #pragma unroll
    for (int j = 0; j < PB; ++j) {
        int bb = b0 + j;
        int cv = (bb < NB) ? cnt[bb] : 0;
        loc[j] = s; s += cv;
    }
    int incl = s;
    #pragma unroll
    for (int d = 1; d < 64; d <<= 1) {
        int t2 = __shfl_up(incl, d);
        if (lane >= d) incl += t2;
    }
    if (lane == 63) wsum[w] = incl;
    __syncthreads();
    int wbase = 0;
    for (int w2 = 0; w2 < w; ++w2) wbase += wsum[w2];
    int base = wbase + incl - s;
    #pragma unroll
    for (int j = 0; j < PB; ++j) {
        int bb = b0 + j;
        if (bb < NB) { off[bb] = base + loc[j]; pos[bb] = base + loc[j]; }
    }
    __syncthreads();

    for (int i = tid; i < m; i += BST) {
        int v = dst[e0 + i];
        int u = src[e0 + i];
        int bb = v >> 6;
        int p = atomicAdd(&pos[bb], 1);
        srt[p] = (unsigned int)u | ((unsigned int)(v & 63) << 16)
               | ((unsigned int)bb << 22);
    }
    __syncthreads();

    for (int i = tid; i < m; i += BST) {
        unsigned int r = srt[i];
        int bb = (int)(r >> 22);
        int gp = gbase[bb] + (i - off[bb]);
        if (gp < BCAP) {
            stag[(size_t)bb * BCAP + gp] = r & 0x3fffffu;
        } else {
            int oi = atomicAdd(ovf_cnt, 1);
            if (oi < OVCAP)
                ovf[oi] = make_int2((int)(r & 0xffffu),
                                    bb * 64 + (int)((r >> 16) & 63));
        }
    }
}

// ============ non-cooperative fallback for the binning path ============
__global__ __launch_bounds__(BST) void count_convert(
    const float* __restrict__ E, const float* __restrict__ W1,
    const float* __restrict__ W2, const int* __restrict__ dst,
    unsigned short* __restrict__ Ebf, unsigned short* __restrict__ W1b,
    unsigned short* __restrict__ W2b, int* __restrict__ cnt_g,
    int n_edges, int nchunk)
{
    const int tid = threadIdx.x;
    if (blockIdx.x >= nchunk) {
        int t = (blockIdx.x - nchunk) * BST + tid;
        convert_item(E, W1, W2, Ebf, W1b, W2b, t);
        return;
    }
    __shared__ int cnt[NB];
    const int e0 = blockIdx.x * ECH;
    const int m = min(ECH, n_edges - e0);
    for (int b = tid; b < NB; b += BST) cnt[b] = 0;
    __syncthreads();
    for (int i = tid; i < m; i += BST)
        atomicAdd(&cnt[dst[e0 + i] >> 6], 1);
    __syncthreads();
    for (int b = tid; b < NB; b += BST)
        cnt_g[(size_t)b * nchunk + blockIdx.x] = cnt[b];
}

__global__ __launch_bounds__(256) void scan_counts(
    int* __restrict__ cnt_g, int* __restrict__ gtail,
    int* __restrict__ ovf_cnt, int nchunk)
{
    if (blockIdx.x == 0 && threadIdx.x == 0) *ovf_cnt = 0;
    const int w = threadIdx.x >> 6, lane = threadIdx.x & 63;
    const int bb = blockIdx.x * 4 + w;
    if (bb >= NB) return;
    int* row = cnt_g + (size_t)bb * nchunk;
    int carry = 0;
    for (int base = 0; base < nchunk; base += 64) {
        int blk = base + lane;
        int v = (blk < nchunk) ? row[blk] : 0;
        int incl = v;
        #pragma unroll
        for (int d = 1; d < 64; d <<= 1) {
            int t = __shfl_up(incl, d);
            if (lane >= d) incl += t;
        }
        if (blk < nchunk) row[blk] = carry + incl - v;
        carry += __shfl(incl, 63);
    }
    if (lane == 0) gtail[bb] = carry;
}

__global__ __launch_bounds__(BST) void scatter_edges(
    const int* __restrict__ src, const int* __restrict__ dst,
    const int* __restrict__ cnt_g, unsigned int* __restrict__ stag,
    int* __restrict__ ovf_cnt, int2* __restrict__ ovf,
    int n_edges, int nchunk)
{
    __shared__ unsigned int srt[ECH];
    __shared__ int cnt[NB], off[NB], pos[NB], gbase[NB];
    __shared__ int wsum[BST / 64];

    const int tid = threadIdx.x;
    const int e0 = blockIdx.x * ECH;
    const int m = min(ECH, n_edges - e0);

    for (int b = tid; b < NB; b += BST) cnt[b] = 0;
    __syncthreads();
    for (int i = tid; i < m; i += BST)
        atomicAdd(&cnt[dst[e0 + i] >> 6], 1);
    for (int b = tid; b < NB; b += BST)
        gbase[b] = cnt_g[(size_t)b * nchunk + blockIdx.x];
    __syncthreads();

    const int lane = tid & 63, w = tid >> 6;
    int b0 = tid * PB;
    int loc[PB]; int s = 0;
    #pragma unroll
    for (int j = 0; j < PB; ++j) {
        int bb = b0 + j;
        int cv = (bb < NB) ? cnt[bb] : 0;
        loc[j] = s; s += cv;
    }
    int incl = s;
    #pragma unroll
    for (int d = 1; d < 64; d <<= 1) {
        int t2 = __shfl_up(incl, d);
        if (lane >= d) incl += t2;
    }
    if (lane == 63) wsum[w] = incl;
    __syncthreads();
    int wbase = 0;
    for (int w2 = 0; w2 < w; ++w2) wbase += wsum[w2];
    int base = wbase + incl - s;
    #pragma unroll
    for (int j = 0; j < PB; ++j) {
        int bb = b0 + j;
        if (bb < NB) { off[bb] = base + loc[j]; pos[bb] = base + loc[j]; }
    }
    __syncthreads();

    for (int i = tid; i < m; i += BST) {
        int v = dst[e0 + i];
        int u = src[e0 + i];
        int bb = v >> 6;
        int p = atomicAdd(&pos[bb], 1);
        srt[p] = (unsigned int)u | ((unsigned int)(v & 63) << 16)
               | ((unsigned int)bb << 22);
    }
    __syncthreads();

    for (int i = tid; i < m; i += BST) {
        unsigned int r = srt[i];
        int bb = (int)(r >> 22);
        int gp = gbase[bb] + (i - off[bb]);
        if (gp < BCAP) {
            stag[(size_t)bb * BCAP + gp] = r & 0x3fffffu;
        } else {
            int oi = atomicAdd(ovf_cnt, 1);
            if (oi < OVCAP)
                ovf[oi] = make_int2((int)(r & 0xffffu),
                                    bb * 64 + (int)((r >> 16) & 63));
        }
    }
}

// ---------------------------------------------------------------------------
// Fused gather + GEMM, plane-quartered gather. One block / bucket (64 nodes).
//   A) LDS counting-sort of the bucket's records by node-low6
//   B) gather in 4 PLANE PASSES: pass q reads only plane q (3.2 MB < 4 MB
//      per-XCD L2) -> the 146 MB L2-miss wall (constant across r0-r5)
//      should collapse toward compulsory traffic.
//      16 lanes per node x 4 nodes per wave, 16-deep dword batches.
//   C) GEMM: wave w owns rows w*16..15 (the rows it gathered -> no barrier).
// ---------------------------------------------------------------------------
__global__ __launch_bounds__(256, 4) void bucket_fused(
    const unsigned short* __restrict__ Ebf, const int* __restrict__ gtail,
    const unsigned int* __restrict__ stag, const int* __restrict__ ovf_cnt,
    const int2* __restrict__ ovf,
    const unsigned short* __restrict__ W1b, const unsigned short* __restrict__ W2b,
    const float* __restrict__ b1, const float* __restrict__ b2,
    float* __restrict__ out)
{
    __shared__ unsigned short sorted[BCAP];       // 4.6 KB
    __shared__ unsigned short Hs[64][HP];         // 17 KB
    __shared__ int cnt[64], off[65], pos[64];
    __shared__ int s_novf;

    const int b = blockIdx.x;
    const int tid = threadIdx.x;
    const int wave = tid >> 6;
    const int lane = tid & 63;
    int len = gtail[b]; len = len < BCAP ? len : BCAP;
    const unsigned int* seg = stag + (size_t)b * BCAP;

    if (tid == 0) { int t = *ovf_cnt; s_novf = t < OVCAP ? t : OVCAP; }
    if (tid < 64) cnt[tid] = 0;
    __syncthreads();
    for (int i = tid; i < len; i += 256)
        atomicAdd(&cnt[(seg[i] >> 16) & 63], 1);
    __syncthreads();
    if (tid < 64) {
        int cv = cnt[tid];
        int incl = cv;
        #pragma unroll
        for (int d = 1; d < 64; d <<= 1) {
            int t2 = __shfl_up(incl, d);
            if (tid >= d) incl += t2;
        }
        off[tid] = incl - cv;
        pos[tid] = incl - cv;
        if (tid == 63) off[64] = incl;
    }
    __syncthreads();
    for (int i = tid; i < len; i += 256) {
        unsigned int r = seg[i];
        int p = atomicAdd(&pos[(r >> 16) & 63], 1);
        sorted[p] = (unsigned short)(r & 0xffffu);
    }
    __syncthreads();
    const int novf = s_novf;

    // ---- gather: 4 plane passes; 16 lanes/node, 4 nodes/wave-iter ----
    const int c = lane & 15;
    const int g2 = lane >> 4;
    for (int q = 0; q < 4; ++q) {
        const unsigned int* Eq = (const unsigned int*)Ebf + (size_t)q * NN * 16;
        for (int s4 = 0; s4 < 4; ++s4) {
            const int nl = wave * 16 + s4 * 4 + g2;
            const int v = b * 64 + nl;
            if (v >= NN) continue;
            float a0 = 0.f, a1 = 0.f;
            int i = off[nl], e1v = off[nl + 1];
            unsigned int r[16];
            for (; i + 16 <= e1v; i += 16) {
                #pragma unroll
                for (int k = 0; k < 16; ++k)
                    r[k] = Eq[(size_t)sorted[i + k] * 16 + c];
                __builtin_amdgcn_sched_barrier(0);   // all 16 in flight
                #pragma unroll
                for (int k = 0; k < 16; ++k) { a0 += bflo(r[k]); a1 += bfhi(r[k]); }
            }
            for (; i + 4 <= e1v; i += 4) {
                #pragma unroll
                for (int k = 0; k < 4; ++k)
                    r[k] = Eq[(size_t)sorted[i + k] * 16 + c];
                __builtin_amdgcn_sched_barrier(0);
                #pragma unroll
                for (int k = 0; k < 4; ++k) { a0 += bflo(r[k]); a1 += bfhi(r[k]); }
            }
            for (; i < e1v; ++i) {
                unsigned int r0 = Eq[(size_t)sorted[i] * 16 + c];
                a0 += bflo(r0); a1 += bfhi(r0);
            }
            if (novf > 0) {
                for (int k = 0; k < novf; ++k) {
                    int2 e = ovf[k];
                    if (e.y == v) {
                        unsigned int r0 = Eq[(size_t)e.x * 16 + c];
                        a0 += bflo(r0); a1 += bfhi(r0);
                    }
                }
            }
            // dword (q*16+c) of row nl == original column order preserved
            *(unsigned int*)&Hs[nl][(q * 16 + c) * 2] = pack2(a0, a1);
        }
    }
    // NO barrier: GEMM wave w consumes exactly the Hs rows wave w wrote.

    // ---- GEMM: wave w -> node rows w*16 .. w*16+15 ----
    const int v0 = b * 64 + wave * 16;
    if (v0 >= NN) return;
    const int m = lane & 15;
    const int quad = lane >> 4;

    bf16x8 aH[4], aE[4];
    const unsigned short* hrow = &Hs[wave * 16 + m][quad * 8];
    #pragma unroll
    for (int ks = 0; ks < 4; ++ks) {
        bf16x8 h8 = *(const bf16x8*)(hrow + ks * 32);
        // plane ks, row v0+m, dwords quad*4.. -> shorts: ks*NN*32 + row*32 + quad*8
        bf16x8 e8 = *(const bf16x8*)(Ebf + (size_t)ks * NN * 32
                                         + (size_t)(v0 + m) * 32 + quad * 8);
        aH[ks] = h8;
        bf16x8 eh;
        #pragma unroll
        for (int j = 0; j < 8; ++j)
            eh[j] = (short)rnebf(sbf(h8[j]) * sbf(e8[j]));
        aE[ks] = eh;
    }

    #pragma unroll
    for (int jt = 0; jt < 8; ++jt) {
        const int j0 = jt * 16;
        const unsigned short* w1r = W1b + (size_t)(j0 + m) * DD + quad * 8;
        const unsigned short* w2r = W2b + (size_t)(j0 + m) * DD + quad * 8;
        f32x4 acc1 = {0.f, 0.f, 0.f, 0.f}, acc2 = {0.f, 0.f, 0.f, 0.f};
        #pragma unroll
        for (int ks = 0; ks < 4; ++ks) {
            bf16x8 bw1 = *(const bf16x8*)(w1r + ks * 32);
            bf16x8 bw2 = *(const bf16x8*)(w2r + ks * 32);
            acc1 = __builtin_amdgcn_mfma_f32_16x16x32_bf16(aH[ks], bw1, acc1, 0, 0, 0);
            acc2 = __builtin_amdgcn_mfma_f32_16x16x32_bf16(aE[ks], bw2, acc2, 0, 0, 0);
        }
        const float bb1 = b1[j0 + m], bb2 = b2[j0 + m];
        #pragma unroll
        for (int i = 0; i < 4; ++i) {
            int row = v0 + quad * 4 + i;
            if (row < NN) {
                float x1 = acc1[i] + bb1; x1 = x1 > 0.f ? x1 : SLOPE * x1;
                float x2 = acc2[i] + bb2; x2 = x2 > 0.f ? x2 : SLOPE * x2;
                out[(size_t)row * DD + j0 + m] = x1 + x2;
            }
        }
    }
}

// ============== minimal fallback (ws too small): fp32 atomics ==============
__global__ __launch_bounds__(256) void scatter_add(
    const float* __restrict__ E, const int* __restrict__ src,
    const int* __restrict__ dst, float* __restrict__ H, int n_edges)
{
    int t = blockIdx.x * 256 + threadIdx.x;
    int e = t >> 5;
    if (e >= n_edges) return;
    int c = t & 31;
    float4 a = ((const float4*)E)[(size_t)src[e] * 32 + c];
    float* hp = H + (size_t)dst[e] * DD + c * 4;
    atomicAdd(hp + 0, a.x); atomicAdd(hp + 1, a.y);
    atomicAdd(hp + 2, a.z); atomicAdd(hp + 3, a.w);
}

__global__ __launch_bounds__(256) void fused_mlp(
    const float* __restrict__ E, const float* __restrict__ H,
    const float* __restrict__ W1, const float* __restrict__ b1,
    const float* __restrict__ W2, const float* __restrict__ b2,
    float* __restrict__ out)
{
    __shared__ float Hsf[32][DD];
    __shared__ float EHs[32][DD];
    __shared__ float W1s[DD][20];
    __shared__ float W2s[DD][20];
    const int tid = threadIdx.x;
    const int v0 = blockIdx.x * 32;
    const int nvalid = min(32, NN - v0);
    for (int i = 0; i < 4; ++i) {
        int f = tid + 256 * i;
        int n = f >> 5, c = f & 31;
        float4 h = make_float4(0.f, 0.f, 0.f, 0.f);
        float4 eh = h;
        if (n < nvalid) {
            h = ((const float4*)H)[(size_t)(v0 + n) * 32 + c];
            float4 e4 = ((const float4*)E)[(size_t)(v0 + n) * 32 + c];
            eh = make_float4(e4.x * h.x, e4.y * h.y, e4.z * h.z, e4.w * h.w);
        }
        *((float4*)&Hsf[n][c * 4]) = h;
        *((float4*)&EHs[n][c * 4]) = eh;
    }
    const int jg = tid & 63;
    const int n0 = (tid >> 6) * 8;
    float acc1a[8] = {}, acc1b[8] = {}, acc2a[8] = {}, acc2b[8] = {};
    for (int t8 = 0; t8 < 8; ++t8) {
        const int k0 = t8 * 16;
        __syncthreads();
        for (int i = 0; i < 8; ++i) {
            int f = tid + 256 * i;
            int j = f >> 4, kk = f & 15;
            W1s[j][kk] = W1[j * DD + k0 + kk];
            W2s[j][kk] = W2[j * DD + k0 + kk];
        }
        __syncthreads();
        for (int c = 0; c < 4; ++c) {
            float4 w1a = *((const float4*)&W1s[jg][c * 4]);
            float4 w1b = *((const float4*)&W1s[jg + 64][c * 4]);
            float4 w2a = *((const float4*)&W2s[jg][c * 4]);
            float4 w2b = *((const float4*)&W2s[jg + 64][c * 4]);
            const int kk = k0 + c * 4;
            for (int n = 0; n < 8; ++n) {
                float4 h = *((const float4*)&Hsf[n0 + n][kk]);
                float4 eh = *((const float4*)&EHs[n0 + n][kk]);
                acc1a[n] += h.x * w1a.x + h.y * w1a.y + h.z * w1a.z + h.w * w1a.w;
                acc1b[n] += h.x * w1b.x + h.y * w1b.y + h.z * w1b.z + h.w * w1b.w;
                acc2a[n] += eh.x * w2a.x + eh.y * w2a.y + eh.z * w2a.z + eh.w * w2a.w;
                acc2b[n] += eh.x * w2b.x + eh.y * w2b.y + eh.z * w2b.z + eh.w * w2b.w;
            }
        }
    }
    const float b1a = b1[jg], b1b = b1[jg + 64];
    const float b2a = b2[jg], b2b = b2[jg + 64];
    for (int n = 0; n < 8; ++n) {
        if (n0 + n < nvalid) {
            const int v = v0 + n0 + n;
            float x1 = acc1a[n] + b1a; x1 = x1 > 0.f ? x1 : SLOPE * x1;
            float x2 = acc2a[n] + b2a; x2 = x2 > 0.f ? x2 : SLOPE * x2;
            out[(size_t)v * DD + jg] = x1 + x2;
            float y1 = acc1b[n] + b1b; y1 = y1 > 0.f ? y1 : SLOPE * y1;
            float y2 = acc2b[n] + b2b; y2 = y2 > 0.f ? y2 : SLOPE * y2;
            out[(size_t)v * DD + jg + 64] = y1 + y2;
        }
    }
}
// ===========================================================================

extern "C" void kernel_launch(void* const* d_in, const int* in_sizes, int n_in,
                              void* d_out, int out_size, void* d_ws, size_t ws_size,
                              hipStream_t stream)
{
    const float* E  = (const float*)d_in[0];
    const float* W1 = (const float*)d_in[1];
    const float* b1 = (const float*)d_in[2];
    const float* W2 = (const float*)d_in[3];
    const float* b2 = (const float*)d_in[4];
    const int* src  = (const int*)d_in[5];
    const int* dst  = (const int*)d_in[6];
    float* out = (float*)d_out;
    const int n_edges = in_sizes[5];

    char* ws = (char*)d_ws;
    auto al = [](size_t x) { return (x + 255) & ~(size_t)255; };

    const int nchunk = (n_edges + ECH - 1) / ECH;

    const size_t off_tail = 0;                                  // NB*4
    const size_t off_ovfc = (size_t)NB * 4;
    const size_t off_ovf  = al(off_ovfc + 4);
    const size_t off_stag = al(off_ovf + (size_t)OVCAP * 8);
    const size_t off_Ebf  = al(off_stag + (size_t)NB * BCAP * 4);
    const size_t off_W1b  = al(off_Ebf + (size_t)NN * DD * 2);
    const size_t off_W2b  = al(off_W1b + (size_t)DD * DD * 2);
    const size_t off_cntg = al(off_W2b + (size_t)DD * DD * 2);
    const size_t need_bf  = off_cntg + (size_t)NB * nchunk * 4; // ~21.8 MB

    if (ws_size >= need_bf) {
        int*  gtail   = (int*)(ws + off_tail);
        int*  ovf_cnt = (int*)(ws + off_ovfc);
        int2* ovf     = (int2*)(ws + off_ovf);
        unsigned int*   stag = (unsigned int*)(ws + off_stag);
        unsigned short* Ebf  = (unsigned short*)(ws + off_Ebf);
        unsigned short* W1b  = (unsigned short*)(ws + off_W1b);
        unsigned short* W2b  = (unsigned short*)(ws + off_W2b);
        int*  cnt_g   = (int*)(ws + off_cntg);

        int ne = n_edges, nc = nchunk;
        void* kargs[] = {
            (void*)&E, (void*)&W1, (void*)&W2, (void*)&src, (void*)&dst,
            (void*)&Ebf, (void*)&W1b, (void*)&W2b, (void*)&cnt_g,
            (void*)&gtail, (void*)&stag, (void*)&ovf_cnt, (void*)&ovf,
            (void*)&ne, (void*)&nc };
        hipError_t cerr = hipLaunchCooperativeKernel(
            (const void*)bin_coop, dim3(nchunk), dim3(BST), kargs, 0, stream);
        if (cerr != hipSuccess) {
            (void)hipGetLastError();   // clear; use split non-coop path
            const int NCV = NN * DD / 8 + 2 * (DD * DD / 8);
            const int ncvb = (NCV + BST - 1) / BST;
            count_convert<<<nchunk + ncvb, BST, 0, stream>>>(
                E, W1, W2, dst, Ebf, W1b, W2b, cnt_g, n_edges, nchunk);
            scan_counts<<<(NB + 3) / 4, 256, 0, stream>>>(
                cnt_g, gtail, ovf_cnt, nchunk);
            scatter_edges<<<nchunk, BST, 0, stream>>>(
                src, dst, cnt_g, stag, ovf_cnt, ovf, n_edges, nchunk);
        }
        bucket_fused<<<NB, 256, 0, stream>>>(
            Ebf, gtail, stag, ovf_cnt, ovf, W1b, W2b, b1, b2, out);
        return;
    }

    // fallback: fp32 atomics into H (= ws if it fits, else out), then fused MLP
    const size_t hbytes = (size_t)NN * DD * sizeof(float);
    float* H = (ws_size >= hbytes) ? (float*)ws : out;
    hipMemsetAsync(H, 0, hbytes, stream);
    scatter_add<<<((n_edges * 32) + 255) / 256, 256, 0, stream>>>(
        E, src, dst, H, n_edges);
    fused_mlp<<<(NN + 31) / 32, 256, 0, stream>>>(E, H, W1, b1, W2, b2, out);
}

// Round 7
// 195.819 us; speedup vs baseline: 2.6731x; 2.6731x over previous
//
#include <hip/hip_runtime.h>

#define NN 50000
#define DD 128
#define SLOPE 0.01f
#define NB 782        // buckets of 64 nodes: bucket = v>>6
#define BCAP 2304     // per-bucket cap; mean 2046, sigma 45 -> +5.7 sigma (+ovf net)
#define NSB 49        // super-buckets of 1024 nodes: sb = v>>10
#define SBW 1024
#define SCAP 34816    // per-super cap; mean 32768, sigma 179 -> +11 sigma
#define ECH1 4096     // edges per level-1 chunk (391 chunks)
#define RSL 2048      // records per rebin slice
#define RS 17         // slices per super (17*2048 = 34816 = SCAP)
#define OVCAP 8192
#define HP 136        // Hs row pitch (bf16): 272B rows -> even b128 bank groups

using bf16x8 = __attribute__((ext_vector_type(8))) short;
using f32x4  = __attribute__((ext_vector_type(4))) float;

// ---------------- bf16 helpers (RNE) ----------------
__device__ inline float bflo(unsigned int w) { return __uint_as_float(w << 16); }
__device__ inline float bfhi(unsigned int w) { return __uint_as_float(w & 0xffff0000u); }
__device__ inline float sbf(short s) {
    return __uint_as_float(((unsigned int)(unsigned short)s) << 16);
}
__device__ inline unsigned int rnebf(float f) {
    unsigned int u = __float_as_uint(f);
    return (u + 0x7fffu + ((u >> 16) & 1u)) >> 16;
}
__device__ inline unsigned int pack2(float lo, float hi) {
    return rnebf(lo) | (rnebf(hi) << 16);
}
__device__ inline void addrow(float* acc, uint4 r) {
    acc[0] += bflo(r.x); acc[1] += bfhi(r.x);
    acc[2] += bflo(r.y); acc[3] += bfhi(r.y);
    acc[4] += bflo(r.z); acc[5] += bfhi(r.z);
    acc[6] += bflo(r.w); acc[7] += bfhi(r.w);
}

// ROW-MAJOR Ebf (r6 lesson: column planes halve line efficiency -- 64B/row
// chunks share 128B lines with unrelated random rows).
__device__ inline void convert_item(
    const float* __restrict__ E, const float* __restrict__ W1,
    const float* __restrict__ W2, unsigned short* __restrict__ Ebf,
    unsigned short* __restrict__ W1b, unsigned short* __restrict__ W2b, int t)
{
    const int NE8 = NN * DD / 8;      // 800000
    const int NW8 = DD * DD / 8;      // 2048
    const float* s; unsigned short* d; int idx;
    if (t < NE8)                { s = E;  d = Ebf; idx = t; }
    else if (t < NE8 + NW8)     { s = W1; d = W1b; idx = t - NE8; }
    else if (t < NE8 + 2 * NW8) { s = W2; d = W2b; idx = t - NE8 - NW8; }
    else return;
    float4 a = ((const float4*)s)[(size_t)idx * 2];
    float4 b = ((const float4*)s)[(size_t)idx * 2 + 1];
    uint4 o;
    o.x = pack2(a.x, a.y); o.y = pack2(a.z, a.w);
    o.z = pack2(b.x, b.y); o.w = pack2(b.z, b.w);
    ((uint4*)d)[idx] = o;
}

// ---------------------------------------------------------------------------
// Level 1: blocks [0,nch1) scatter ECH1 edges each into 49 super-buckets
// (runs of ~84 records -> ~334 B/line vs the old 16 B/line: kills the 8x
// write amplification bin_coop's counters exposed, WRITE 50 MB for 6.4 MB
// logical). Edges held in REGISTERS (single read). Bulk base reservation =
// one global atomicAdd per nonempty super per block (~19K total; r2 proved
// 200K of these are not a bottleneck). Blocks [nch1,..): fp32->bf16 convert.
// Record: u (bits 0..15) | v&1023 (bits 16..25).
// ---------------------------------------------------------------------------
__global__ __launch_bounds__(512) void scatter_convert(
    const float* __restrict__ E, const float* __restrict__ W1,
    const float* __restrict__ W2, const int* __restrict__ src,
    const int* __restrict__ dst, unsigned short* __restrict__ Ebf,
    unsigned short* __restrict__ W1b, unsigned short* __restrict__ W2b,
    int* __restrict__ gtail1, unsigned int* __restrict__ stag1,
    int* __restrict__ ovf_cnt, int2* __restrict__ ovf,
    int n_edges, int nch1)
{
    const int tid = threadIdx.x;
    if (blockIdx.x >= nch1) {
        convert_item(E, W1, W2, Ebf, W1b, W2b,
                     (blockIdx.x - nch1) * 512 + tid);
        return;
    }

    __shared__ int cnt49[NSB];
    const int e0 = blockIdx.x * ECH1;
    int vv[8], uu[8];

    if (tid < NSB) cnt49[tid] = 0;
    __syncthreads();
    #pragma unroll
    for (int k = 0; k < 8; ++k) {
        int idx = e0 + tid + k * 512;
        if (idx < n_edges) {
            vv[k] = dst[idx]; uu[k] = src[idx];
            atomicAdd(&cnt49[vv[k] >> 10], 1);
        } else vv[k] = -1;
    }
    __syncthreads();
    if (tid < NSB) {
        int c = cnt49[tid];
        cnt49[tid] = c ? atomicAdd(&gtail1[tid], c) : 0;  // -> running pos
    }
    __syncthreads();
    #pragma unroll
    for (int k = 0; k < 8; ++k) {
        if (vv[k] < 0) continue;
        int sb = vv[k] >> 10;
        int p = atomicAdd(&cnt49[sb], 1);
        if (p < SCAP) {
            stag1[(size_t)sb * SCAP + p] =
                (unsigned int)uu[k] | ((unsigned int)(vv[k] & 1023) << 16);
        } else {
            int oi = atomicAdd(ovf_cnt, 1);
            if (oi < OVCAP) ovf[oi] = make_int2(uu[k], vv[k]);
        }
    }
}

// ---------------------------------------------------------------------------
// Level 2: block (sb,slice) re-bins RSL records of super sb into its 16
// final buckets. Coalesced segment reads, records in registers, bulk base
// reservation on gtail[], runs of ~128 -> coalesced writes.
// ---------------------------------------------------------------------------
__global__ __launch_bounds__(256) void rebin(
    const int* __restrict__ gtail1, const unsigned int* __restrict__ stag1,
    int* __restrict__ gtail, unsigned int* __restrict__ stag,
    int* __restrict__ ovf_cnt, int2* __restrict__ ovf)
{
    const int sb = blockIdx.x / RS, sl = blockIdx.x % RS;
    const int tid = threadIdx.x;
    int len = gtail1[sb]; len = len < SCAP ? len : SCAP;
    const int i0 = sl * RSL;
    const int i1 = min(i0 + RSL, len);

    __shared__ int cnt16[16], pos16[16];
    if (tid < 16) cnt16[tid] = 0;
    __syncthreads();

    unsigned int r[8];
    const unsigned int* seg = stag1 + (size_t)sb * SCAP;
    #pragma unroll
    for (int k = 0; k < 8; ++k) {
        int idx = i0 + tid + k * 256;
        if (idx < i1) {
            r[k] = seg[idx];
            atomicAdd(&cnt16[(r[k] >> 22) & 15], 1);
        } else r[k] = 0xffffffffu;     // recs are <= 0x03ffffff: safe sentinel
    }
    __syncthreads();
    if (tid < 16) {
        int c = cnt16[tid];
        int bb = sb * 16 + tid;
        pos16[tid] = (c && bb < NB) ? atomicAdd(&gtail[bb], c) : 0;
    }
    __syncthreads();
    #pragma unroll
    for (int k = 0; k < 8; ++k) {
        if (r[k] == 0xffffffffu) continue;
        int j = (r[k] >> 22) & 15;
        int p = atomicAdd(&pos16[j], 1);
        int bb = sb * 16 + j;
        if (p < BCAP) {
            stag[(size_t)bb * BCAP + p] = r[k] & 0x3fffffu;
        } else {
            int oi = atomicAdd(ovf_cnt, 1);
            if (oi < OVCAP)
                ovf[oi] = make_int2((int)(r[k] & 0xffffu),
                                    sb * SBW + (int)((r[k] >> 16) & 1023));
        }
    }
}

// ---------------------------------------------------------------------------
// Fused gather + GEMM -- r4 version verbatim (proven 84-85 us, row-major).
// ---------------------------------------------------------------------------
__global__ __launch_bounds__(256, 4) void bucket_fused(
    const unsigned short* __restrict__ Ebf, const int* __restrict__ gtail,
    const unsigned int* __restrict__ stag, const int* __restrict__ ovf_cnt,
    const int2* __restrict__ ovf,
    const unsigned short* __restrict__ W1b, const unsigned short* __restrict__ W2b,
    const float* __restrict__ b1, const float* __restrict__ b2,
    float* __restrict__ out)
{
    __shared__ unsigned short sorted[BCAP];       // 4.6 KB
    __shared__ unsigned short Hs[64][HP];         // 17 KB
    __shared__ int cnt[64], off[65], pos[64];
    __shared__ int s_novf;

    const int b = blockIdx.x;
    const int tid = threadIdx.x;
    int len = gtail[b]; len = len < BCAP ? len : BCAP;
    const unsigned int* seg = stag + (size_t)b * BCAP;

    if (tid == 0) { int t = *ovf_cnt; s_novf = t < OVCAP ? t : OVCAP; }
    if (tid < 64) cnt[tid] = 0;
    __syncthreads();
    for (int i = tid; i < len; i += 256)
        atomicAdd(&cnt[(seg[i] >> 16) & 63], 1);
    __syncthreads();
    if (tid < 64) {
        int cv = cnt[tid];
        int incl = cv;
        #pragma unroll
        for (int d = 1; d < 64; d <<= 1) {
            int t2 = __shfl_up(incl, d);
            if (tid >= d) incl += t2;
        }
        off[tid] = incl - cv;
        pos[tid] = incl - cv;
        if (tid == 63) off[64] = incl;
    }
    __syncthreads();
    for (int i = tid; i < len; i += 256) {
        unsigned int r = seg[i];
        int p = atomicAdd(&pos[(r >> 16) & 63], 1);
        sorted[p] = (unsigned short)(r & 0xffffu);
    }
    __syncthreads();
    const int novf = s_novf;

    // ---- gather: 16 lanes per node x 16 nodes per pass, 4 passes ----
    const int g = tid >> 4;
    const int c = tid & 15;
    const uint4* E4 = (const uint4*)Ebf;
    for (int p4 = 0; p4 < 4; ++p4) {
        int nl = p4 * 16 + g;
        int v = b * 64 + nl;
        if (v >= NN) continue;
        float acc[8] = {};
        int i = off[nl], e1 = off[nl + 1];
        uint4 r[16];
        for (; i + 16 <= e1; i += 16) {
            #pragma unroll
            for (int k = 0; k < 16; ++k)
                r[k] = E4[(size_t)sorted[i + k] * 16 + c];
            __builtin_amdgcn_sched_barrier(0);
            #pragma unroll
            for (int k = 0; k < 16; ++k) addrow(acc, r[k]);
        }
        for (; i + 4 <= e1; i += 4) {
            #pragma unroll
            for (int k = 0; k < 4; ++k)
                r[k] = E4[(size_t)sorted[i + k] * 16 + c];
            __builtin_amdgcn_sched_barrier(0);
            #pragma unroll
            for (int k = 0; k < 4; ++k) addrow(acc, r[k]);
        }
        for (; i < e1; ++i) addrow(acc, E4[(size_t)sorted[i] * 16 + c]);

        if (novf > 0) {                    // rare path: fold overflow edges
            for (int k = 0; k < novf; ++k) {
                int2 e = ovf[k];
                if (e.y == v) addrow(acc, E4[(size_t)e.x * 16 + c]);
            }
        }
        uint4 o;
        o.x = pack2(acc[0], acc[1]); o.y = pack2(acc[2], acc[3]);
        o.z = pack2(acc[4], acc[5]); o.w = pack2(acc[6], acc[7]);
        *(uint4*)&Hs[nl][c * 8] = o;
    }
    __syncthreads();

    // ---- GEMM: wave w -> node rows w*16 .. w*16+15 ----
    const int wave = tid >> 6;
    const int lane = tid & 63;
    const int v0 = b * 64 + wave * 16;
    if (v0 >= NN) return;
    const int m = lane & 15;
    const int quad = lane >> 4;

    bf16x8 aH[4], aE[4];
    const unsigned short* hrow = &Hs[wave * 16 + m][quad * 8];
    const unsigned short* erow = Ebf + (size_t)(v0 + m) * DD + quad * 8;
    #pragma unroll
    for (int ks = 0; ks < 4; ++ks) {
        bf16x8 h8 = *(const bf16x8*)(hrow + ks * 32);
        bf16x8 e8 = *(const bf16x8*)(erow + ks * 32);
        aH[ks] = h8;
        bf16x8 eh;
        #pragma unroll
        for (int j = 0; j < 8; ++j)
            eh[j] = (short)rnebf(sbf(h8[j]) * sbf(e8[j]));
        aE[ks] = eh;
    }

    #pragma unroll
    for (int jt = 0; jt < 8; ++jt) {
        const int j0 = jt * 16;
        const unsigned short* w1r = W1b + (size_t)(j0 + m) * DD + quad * 8;
        const unsigned short* w2r = W2b + (size_t)(j0 + m) * DD + quad * 8;
        f32x4 acc1 = {0.f, 0.f, 0.f, 0.f}, acc2 = {0.f, 0.f, 0.f, 0.f};
        #pragma unroll
        for (int ks = 0; ks < 4; ++ks) {
            bf16x8 bw1 = *(const bf16x8*)(w1r + ks * 32);
            bf16x8 bw2 = *(const bf16x8*)(w2r + ks * 32);
            acc1 = __builtin_amdgcn_mfma_f32_16x16x32_bf16(aH[ks], bw1, acc1, 0, 0, 0);
            acc2 = __builtin_amdgcn_mfma_f32_16x16x32_bf16(aE[ks], bw2, acc2, 0, 0, 0);
        }
        const float bb1 = b1[j0 + m], bb2 = b2[j0 + m];
        #pragma unroll
        for (int i = 0; i < 4; ++i) {
            int row = v0 + quad * 4 + i;
            if (row < NN) {
                float x1 = acc1[i] + bb1; x1 = x1 > 0.f ? x1 : SLOPE * x1;
                float x2 = acc2[i] + bb2; x2 = x2 > 0.f ? x2 : SLOPE * x2;
                out[(size_t)row * DD + j0 + m] = x1 + x2;
            }
        }
    }
}

// ============== minimal fallback (ws too small): fp32 atomics ==============
__global__ __launch_bounds__(256) void scatter_add(
    const float* __restrict__ E, const int* __restrict__ src,
    const int* __restrict__ dst, float* __restrict__ H, int n_edges)
{
    int t = blockIdx.x * 256 + threadIdx.x;
    int e = t >> 5;
    if (e >= n_edges) return;
    int c = t & 31;
    float4 a = ((const float4*)E)[(size_t)src[e] * 32 + c];
    float* hp = H + (size_t)dst[e] * DD + c * 4;
    atomicAdd(hp + 0, a.x); atomicAdd(hp + 1, a.y);
    atomicAdd(hp + 2, a.z); atomicAdd(hp + 3, a.w);
}

__global__ __launch_bounds__(256) void fused_mlp(
    const float* __restrict__ E, const float* __restrict__ H,
    const float* __restrict__ W1, const float* __restrict__ b1,
    const float* __restrict__ W2, const float* __restrict__ b2,
    float* __restrict__ out)
{
    __shared__ float Hsf[32][DD];
    __shared__ float EHs[32][DD];
    __shared__ float W1s[DD][20];
    __shared__ float W2s[DD][20];
    const int tid = threadIdx.x;
    const int v0 = blockIdx.x * 32;
    const int nvalid = min(32, NN - v0);
    for (int i = 0; i < 4; ++i) {
        int f = tid + 256 * i;
        int n = f >> 5, c = f & 31;
        float4 h = make_float4(0.f, 0.f, 0.f, 0.f);
        float4 eh = h;
        if (n < nvalid) {
            h = ((const float4*)H)[(size_t)(v0 + n) * 32 + c];
            float4 e4 = ((const float4*)E)[(size_t)(v0 + n) * 32 + c];
            eh = make_float4(e4.x * h.x, e4.y * h.y, e4.z * h.z, e4.w * h.w);
        }
        *((float4*)&Hsf[n][c * 4]) = h;
        *((float4*)&EHs[n][c * 4]) = eh;
    }
    const int jg = tid & 63;
    const int n0 = (tid >> 6) * 8;
    float acc1a[8] = {}, acc1b[8] = {}, acc2a[8] = {}, acc2b[8] = {};
    for (int t8 = 0; t8 < 8; ++t8) {
        const int k0 = t8 * 16;
        __syncthreads();
        for (int i = 0; i < 8; ++i) {
            int f = tid + 256 * i;
            int j = f >> 4, kk = f & 15;
            W1s[j][kk] = W1[j * DD + k0 + kk];
            W2s[j][kk] = W2[j * DD + k0 + kk];
        }
        __syncthreads();
        for (int c = 0; c < 4; ++c) {
            float4 w1a = *((const float4*)&W1s[jg][c * 4]);
            float4 w1b = *((const float4*)&W1s[jg + 64][c * 4]);
            float4 w2a = *((const float4*)&W2s[jg][c * 4]);
            float4 w2b = *((const float4*)&W2s[jg + 64][c * 4]);
            const int kk = k0 + c * 4;
            for (int n = 0; n < 8; ++n) {
                float4 h = *((const float4*)&Hsf[n0 + n][kk]);
                float4 eh = *((const float4*)&EHs[n0 + n][kk]);
                acc1a[n] += h.x * w1a.x + h.y * w1a.y + h.z * w1a.z + h.w * w1a.w;
                acc1b[n] += h.x * w1b.x + h.y * w1b.y + h.z * w1b.z + h.w * w1b.w;
                acc2a[n] += eh.x * w2a.x + eh.y * w2a.y + eh.z * w2a.z + eh.w * w2a.w;
                acc2b[n] += eh.x * w2b.x + eh.y * w2b.y + eh.z * w2b.z + eh.w * w2b.w;
            }
        }
    }
    const float b1a = b1[jg], b1b = b1[jg + 64];
    const float b2a = b2[jg], b2b = b2[jg + 64];
    for (int n = 0; n < 8; ++n) {
        if (n0 + n < nvalid) {
            const int v = v0 + n0 + n;
            float x1 = acc1a[n] + b1a; x1 = x1 > 0.f ? x1 : SLOPE * x1;
            float x2 = acc2a[n] + b2a; x2 = x2 > 0.f ? x2 : SLOPE * x2;
            out[(size_t)v * DD + jg] = x1 + x2;
            float y1 = acc1b[n] + b1b; y1 = y1 > 0.f ? y1 : SLOPE * y1;
            float y2 = acc2b[n] + b2b; y2 = y2 > 0.f ? y2 : SLOPE * y2;
            out[(size_t)v * DD + jg + 64] = y1 + y2;
        }
    }
}
// ===========================================================================

extern "C" void kernel_launch(void* const* d_in, const int* in_sizes, int n_in,
                              void* d_out, int out_size, void* d_ws, size_t ws_size,
                              hipStream_t stream)
{
    const float* E  = (const float*)d_in[0];
    const float* W1 = (const float*)d_in[1];
    const float* b1 = (const float*)d_in[2];
    const float* W2 = (const float*)d_in[3];
    const float* b2 = (const float*)d_in[4];
    const int* src  = (const int*)d_in[5];
    const int* dst  = (const int*)d_in[6];
    float* out = (float*)d_out;
    const int n_edges = in_sizes[5];

    char* ws = (char*)d_ws;
    auto al = [](size_t x) { return (x + 255) & ~(size_t)255; };

    const int nch1 = (n_edges + ECH1 - 1) / ECH1;

    // counters: gtail1[NSB] | ovf_cnt[1] | gtail[NB]  (one small memset)
    const size_t ctr_ints  = NSB + 1 + NB;
    const size_t off_ovf   = al(ctr_ints * 4);
    const size_t off_stag1 = al(off_ovf + (size_t)OVCAP * 8);
    const size_t off_stag  = al(off_stag1 + (size_t)NSB * SCAP * 4);
    const size_t off_Ebf   = al(off_stag + (size_t)NB * BCAP * 4);
    const size_t off_W1b   = al(off_Ebf + (size_t)NN * DD * 2);
    const size_t off_W2b   = al(off_W1b + (size_t)DD * DD * 2);
    const size_t need_bf   = off_W2b + (size_t)DD * DD * 2;     // ~27 MB

    if (ws_size >= need_bf) {
        int*  gtail1  = (int*)ws;
        int*  ovf_cnt = gtail1 + NSB;
        int*  gtail   = gtail1 + NSB + 1;
        int2* ovf     = (int2*)(ws + off_ovf);
        unsigned int*   stag1 = (unsigned int*)(ws + off_stag1);
        unsigned int*   stag  = (unsigned int*)(ws + off_stag);
        unsigned short* Ebf   = (unsigned short*)(ws + off_Ebf);
        unsigned short* W1b   = (unsigned short*)(ws + off_W1b);
        unsigned short* W2b   = (unsigned short*)(ws + off_W2b);

        const int NCV  = NN * DD / 8 + 2 * (DD * DD / 8);
        const int ncvb = (NCV + 511) / 512;

        hipMemsetAsync(ws, 0, ctr_ints * 4, stream);
        scatter_convert<<<nch1 + ncvb, 512, 0, stream>>>(
            E, W1, W2, src, dst, Ebf, W1b, W2b,
            gtail1, stag1, ovf_cnt, ovf, n_edges, nch1);
        rebin<<<NSB * RS, 256, 0, stream>>>(
            gtail1, stag1, gtail, stag, ovf_cnt, ovf);
        bucket_fused<<<NB, 256, 0, stream>>>(
            Ebf, gtail, stag, ovf_cnt, ovf, W1b, W2b, b1, b2, out);
        return;
    }

    // fallback: fp32 atomics into H (= ws if it fits, else out), then fused MLP
    const size_t hbytes = (size_t)NN * DD * sizeof(float);
    float* H = (ws_size >= hbytes) ? (float*)ws : out;
    hipMemsetAsync(H, 0, hbytes, stream);
    scatter_add<<<((n_edges * 32) + 255) / 256, 256, 0, stream>>>(
        E, src, dst, H, n_edges);
    fused_mlp<<<(NN + 31) / 32, 256, 0, stream>>>(E, H, W1, b1, W2, b2, out);
}

// Round 10
// 193.544 us; speedup vs baseline: 2.7045x; 1.0118x over previous
//
#include <hip/hip_runtime.h>

#define NN 50000
#define DD 128
#define SLOPE 0.01f
#define NB 782        // buckets of 64 nodes: bucket = v>>6
#define BCAP 2304     // per-bucket cap; mean 2046, sigma 45 -> +5.7 sigma (+ovf net)
#define NSB 49        // super-buckets of 1024 nodes: sb = v>>10
#define SBW 1024
#define SCAP 34816    // per-super cap; mean 32768, sigma 179 -> +11 sigma
#define ECH1 4096     // edges per level-1 chunk (391 chunks)
#define RSL 2048      // records per rebin slice
#define RS 17         // slices per super (17*2048 = 34816 = SCAP)
#define OVCAP 8192
#define HP 136        // Hs row pitch (bf16) in the fused-fallback kernel

using bf16x8 = __attribute__((ext_vector_type(8))) short;
using f32x4  = __attribute__((ext_vector_type(4))) float;

// ---------------- bf16 helpers (RNE) ----------------
__device__ inline float bflo(unsigned int w) { return __uint_as_float(w << 16); }
__device__ inline float bfhi(unsigned int w) { return __uint_as_float(w & 0xffff0000u); }
__device__ inline float sbf(short s) {
    return __uint_as_float(((unsigned int)(unsigned short)s) << 16);
}
__device__ inline unsigned int rnebf(float f) {
    unsigned int u = __float_as_uint(f);
    return (u + 0x7fffu + ((u >> 16) & 1u)) >> 16;
}
__device__ inline unsigned int pack2(float lo, float hi) {
    return rnebf(lo) | (rnebf(hi) << 16);
}
__device__ inline void addrow(float* acc, uint4 r) {
    acc[0] += bflo(r.x); acc[1] += bfhi(r.x);
    acc[2] += bflo(r.y); acc[3] += bfhi(r.y);
    acc[4] += bflo(r.z); acc[5] += bfhi(r.z);
    acc[6] += bflo(r.w); acc[7] += bfhi(r.w);
}

// ROW-MAJOR Ebf (r6 lesson: column planes halve line efficiency).
__device__ inline void convert_item(
    const float* __restrict__ E, const float* __restrict__ W1,
    const float* __restrict__ W2, unsigned short* __restrict__ Ebf,
    unsigned short* __restrict__ W1b, unsigned short* __restrict__ W2b, int t)
{
    const int NE8 = NN * DD / 8;      // 800000
    const int NW8 = DD * DD / 8;      // 2048
    const float* s; unsigned short* d; int idx;
    if (t < NE8)                { s = E;  d = Ebf; idx = t; }
    else if (t < NE8 + NW8)     { s = W1; d = W1b; idx = t - NE8; }
    else if (t < NE8 + 2 * NW8) { s = W2; d = W2b; idx = t - NE8 - NW8; }
    else return;
    float4 a = ((const float4*)s)[(size_t)idx * 2];
    float4 b = ((const float4*)s)[(size_t)idx * 2 + 1];
    uint4 o;
    o.x = pack2(a.x, a.y); o.y = pack2(a.z, a.w);
    o.z = pack2(b.x, b.y); o.w = pack2(b.z, b.w);
    ((uint4*)d)[idx] = o;
}

// ---------------------------------------------------------------------------
// Level-1 binning + convert (r7 verbatim).
// Record: u (bits 0..15) | v&1023 (bits 16..25).
// ---------------------------------------------------------------------------
__global__ __launch_bounds__(512) void scatter_convert(
    const float* __restrict__ E, const float* __restrict__ W1,
    const float* __restrict__ W2, const int* __restrict__ src,
    const int* __restrict__ dst, unsigned short* __restrict__ Ebf,
    unsigned short* __restrict__ W1b, unsigned short* __restrict__ W2b,
    int* __restrict__ gtail1, unsigned int* __restrict__ stag1,
    int* __restrict__ ovf_cnt, int2* __restrict__ ovf,
    int n_edges, int nch1)
{
    const int tid = threadIdx.x;
    if (blockIdx.x >= nch1) {
        convert_item(E, W1, W2, Ebf, W1b, W2b,
                     (blockIdx.x - nch1) * 512 + tid);
        return;
    }

    __shared__ int cnt49[NSB];
    const int e0 = blockIdx.x * ECH1;
    int vv[8], uu[8];

    if (tid < NSB) cnt49[tid] = 0;
    __syncthreads();
    #pragma unroll
    for (int k = 0; k < 8; ++k) {
        int idx = e0 + tid + k * 512;
        if (idx < n_edges) {
            vv[k] = dst[idx]; uu[k] = src[idx];
            atomicAdd(&cnt49[vv[k] >> 10], 1);
        } else vv[k] = -1;
    }
    __syncthreads();
    if (tid < NSB) {
        int c = cnt49[tid];
        cnt49[tid] = c ? atomicAdd(&gtail1[tid], c) : 0;  // -> running pos
    }
    __syncthreads();
    #pragma unroll
    for (int k = 0; k < 8; ++k) {
        if (vv[k] < 0) continue;
        int sb = vv[k] >> 10;
        int p = atomicAdd(&cnt49[sb], 1);
        if (p < SCAP) {
            stag1[(size_t)sb * SCAP + p] =
                (unsigned int)uu[k] | ((unsigned int)(vv[k] & 1023) << 16);
        } else {
            int oi = atomicAdd(ovf_cnt, 1);
            if (oi < OVCAP) ovf[oi] = make_int2(uu[k], vv[k]);
        }
    }
}

// ---------------------------------------------------------------------------
// Level-2 rebin (r7 verbatim).
// ---------------------------------------------------------------------------
__global__ __launch_bounds__(256) void rebin(
    const int* __restrict__ gtail1, const unsigned int* __restrict__ stag1,
    int* __restrict__ gtail, unsigned int* __restrict__ stag,
    int* __restrict__ ovf_cnt, int2* __restrict__ ovf)
{
    const int sb = blockIdx.x / RS, sl = blockIdx.x % RS;
    const int tid = threadIdx.x;
    int len = gtail1[sb]; len = len < SCAP ? len : SCAP;
    const int i0 = sl * RSL;
    const int i1 = min(i0 + RSL, len);

    __shared__ int cnt16[16], pos16[16];
    if (tid < 16) cnt16[tid] = 0;
    __syncthreads();

    unsigned int r[8];
    const unsigned int* seg = stag1 + (size_t)sb * SCAP;
    #pragma unroll
    for (int k = 0; k < 8; ++k) {
        int idx = i0 + tid + k * 256;
        if (idx < i1) {
            r[k] = seg[idx];
            atomicAdd(&cnt16[(r[k] >> 22) & 15], 1);
        } else r[k] = 0xffffffffu;
    }
    __syncthreads();
    if (tid < 16) {
        int c = cnt16[tid];
        int bb = sb * 16 + tid;
        pos16[tid] = (c && bb < NB) ? atomicAdd(&gtail[bb], c) : 0;
    }
    __syncthreads();
    #pragma unroll
    for (int k = 0; k < 8; ++k) {
        if (r[k] == 0xffffffffu) continue;
        int j = (r[k] >> 22) & 15;
        int p = atomicAdd(&pos16[j], 1);
        int bb = sb * 16 + j;
        if (p < BCAP) {
            stag[(size_t)bb * BCAP + p] = r[k] & 0x3fffffu;
        } else {
            int oi = atomicAdd(ovf_cnt, 1);
            if (oi < OVCAP)
                ovf[oi] = make_int2((int)(r[k] & 0xffffu),
                                    sb * SBW + (int)((r[k] >> 16) & 1023));
        }
    }
}

// ---------------------------------------------------------------------------
// bucket_gather: grid NB*2 -- block (b,h) gathers COLUMN-HALF h (one 128B
// line per edge) of bucket b into fp32 Hf.  Two levers vs the fused 85us:
//  (1) 2x blocks -> 2x independent per-CU miss streams (r1/r2/r5 showed
//      per-wave depth is capped by the CU's outstanding-line trackers);
//  (2) BAND-SORTED order: LDS sort key = node<<4 | src>>12, so every group
//      walks Ebf in ascending ~4K-row bands; grid-wide the requests
//      concentrate in a moving ~400KB band -> L2/L3-hot -> lower latency.
// ---------------------------------------------------------------------------
__global__ __launch_bounds__(256, 4) void bucket_gather(
    const unsigned short* __restrict__ Ebf, const int* __restrict__ gtail,
    const unsigned int* __restrict__ stag, const int* __restrict__ ovf_cnt,
    const int2* __restrict__ ovf, float* __restrict__ Hf)
{
    __shared__ unsigned short sorted[BCAP];   // 4.6 KB
    __shared__ int cnt1k[1024];               // counts -> placement pos
    __shared__ int bstart[1025];              // bin exclusive bases
    __shared__ int wsum[4];
    __shared__ int s_novf;

    const int b = blockIdx.x >> 1;
    const int h = blockIdx.x & 1;
    const int tid = threadIdx.x;
    int len = gtail[b]; len = len < BCAP ? len : BCAP;
    const unsigned int* seg = stag + (size_t)b * BCAP;

    if (tid == 0) { int t = *ovf_cnt; s_novf = t < OVCAP ? t : OVCAP; }
    #pragma unroll
    for (int j = 0; j < 4; ++j) cnt1k[tid * 4 + j] = 0;
    __syncthreads();
    for (int i = tid; i < len; i += 256) {
        unsigned int r = seg[i];
        int key = (int)(((r >> 16) & 63) << 4) | (int)((r & 0xffffu) >> 12);
        atomicAdd(&cnt1k[key], 1);
    }
    __syncthreads();
    // exclusive scan of 1024 counters: 4 per thread + wave scan + wave bases
    {
        const int lane = tid & 63, w = tid >> 6;
        int c[4], loc[4]; int s = 0;
        #pragma unroll
        for (int j = 0; j < 4; ++j) {
            c[j] = cnt1k[tid * 4 + j]; loc[j] = s; s += c[j];
        }
        int incl = s;
        #pragma unroll
        for (int d = 1; d < 64; d <<= 1) {
            int t2 = __shfl_up(incl, d);
            if (lane >= d) incl += t2;
        }
        if (lane == 63) wsum[w] = incl;
        __syncthreads();
        int wbase = 0;
        for (int w2 = 0; w2 < w; ++w2) wbase += wsum[w2];
        int base = wbase + incl - s;
        #pragma unroll
        for (int j = 0; j < 4; ++j) {
            bstart[tid * 4 + j] = base + loc[j];
            cnt1k[tid * 4 + j]  = base + loc[j];   // becomes pos
        }
        if (tid == 255) bstart[1024] = base + s;   // == len
    }
    __syncthreads();
    for (int i = tid; i < len; i += 256) {
        unsigned int r = seg[i];
        int key = (int)(((r >> 16) & 63) << 4) | (int)((r & 0xffffu) >> 12);
        int p = atomicAdd(&cnt1k[key], 1);
        sorted[p] = (unsigned short)(r & 0xffffu);
    }
    __syncthreads();
    const int novf = s_novf;

    // ---- gather: 8 lanes per node (one 128B line), 32 nodes/pass, 2 passes
    const int g = tid >> 3;
    const int c = tid & 7;
    const uint4* E4 = (const uint4*)Ebf;
    for (int p2 = 0; p2 < 2; ++p2) {
        int nl = p2 * 32 + g;
        int v = b * 64 + nl;
        if (v >= NN) continue;
        float acc[8] = {};
        int i = bstart[nl << 4], e1 = bstart[(nl + 1) << 4];
        uint4 r[8];
        for (; i + 8 <= e1; i += 8) {
            #pragma unroll
            for (int k = 0; k < 8; ++k)
                r[k] = E4[(size_t)sorted[i + k] * 16 + h * 8 + c];
            __builtin_amdgcn_sched_barrier(0);
            #pragma unroll
            for (int k = 0; k < 8; ++k) addrow(acc, r[k]);
        }
        for (; i + 2 <= e1; i += 2) {
            uint4 r0 = E4[(size_t)sorted[i]     * 16 + h * 8 + c];
            uint4 r1 = E4[(size_t)sorted[i + 1] * 16 + h * 8 + c];
            addrow(acc, r0); addrow(acc, r1);
        }
        if (i < e1) addrow(acc, E4[(size_t)sorted[i] * 16 + h * 8 + c]);

        if (novf > 0) {                    // rare path: fold overflow edges
            for (int k = 0; k < novf; ++k) {
                int2 e = ovf[k];
                if (e.y == v) addrow(acc, E4[(size_t)e.x * 16 + h * 8 + c]);
            }
        }
        float* o = Hf + (size_t)v * DD + h * 64 + c * 8;
        *(float4*)o       = make_float4(acc[0], acc[1], acc[2], acc[3]);
        *(float4*)(o + 4) = make_float4(acc[4], acc[5], acc[6], acc[7]);
    }
}

// ---------------------------------------------------------------------------
// bucket_gemm: grid NB; wave w -> rows w*16..+15. Reads fp32 Hf (rounds to
// bf16 once -> numerics identical to the fused path), Ebf, W; MFMA + leaky.
// ---------------------------------------------------------------------------
__global__ __launch_bounds__(256) void bucket_gemm(
    const float* __restrict__ Hf, const unsigned short* __restrict__ Ebf,
    const unsigned short* __restrict__ W1b, const unsigned short* __restrict__ W2b,
    const float* __restrict__ b1, const float* __restrict__ b2,
    float* __restrict__ out)
{
    const int b = blockIdx.x;
    const int tid = threadIdx.x;
    const int wave = tid >> 6;
    const int lane = tid & 63;
    const int v0 = b * 64 + wave * 16;
    if (v0 >= NN) return;
    const int m = lane & 15;
    const int quad = lane >> 4;

    bf16x8 aH[4], aE[4];
    const float* hrow = Hf + (size_t)(v0 + m) * DD + quad * 8;
    const unsigned short* erow = Ebf + (size_t)(v0 + m) * DD + quad * 8;
    #pragma unroll
    for (int ks = 0; ks < 4; ++ks) {
        float4 f0 = *(const float4*)(hrow + ks * 32);
        float4 f1 = *(const float4*)(hrow + ks * 32 + 4);
        bf16x8 e8 = *(const bf16x8*)(erow + ks * 32);
        bf16x8 h8, eh;
        h8[0] = (short)rnebf(f0.x); h8[1] = (short)rnebf(f0.y);
        h8[2] = (short)rnebf(f0.z); h8[3] = (short)rnebf(f0.w);
        h8[4] = (short)rnebf(f1.x); h8[5] = (short)rnebf(f1.y);
        h8[6] = (short)rnebf(f1.z); h8[7] = (short)rnebf(f1.w);
        #pragma unroll
        for (int j = 0; j < 8; ++j)
            eh[j] = (short)rnebf(sbf(h8[j]) * sbf(e8[j]));
        aH[ks] = h8; aE[ks] = eh;
    }

    #pragma unroll
    for (int jt = 0; jt < 8; ++jt) {
        const int j0 = jt * 16;
        const unsigned short* w1r = W1b + (size_t)(j0 + m) * DD + quad * 8;
        const unsigned short* w2r = W2b + (size_t)(j0 + m) * DD + quad * 8;
        f32x4 acc1 = {0.f, 0.f, 0.f, 0.f}, acc2 = {0.f, 0.f, 0.f, 0.f};
        #pragma unroll
        for (int ks = 0; ks < 4; ++ks) {
            bf16x8 bw1 = *(const bf16x8*)(w1r + ks * 32);
            bf16x8 bw2 = *(const bf16x8*)(w2r + ks * 32);
            acc1 = __builtin_amdgcn_mfma_f32_16x16x32_bf16(aH[ks], bw1, acc1, 0, 0, 0);
            acc2 = __builtin_amdgcn_mfma_f32_16x16x32_bf16(aE[ks], bw2, acc2, 0, 0, 0);
        }
        const float bb1 = b1[j0 + m], bb2 = b2[j0 + m];
        #pragma unroll
        for (int i = 0; i < 4; ++i) {
            int row = v0 + quad * 4 + i;
            if (row < NN) {
                float x1 = acc1[i] + bb1; x1 = x1 > 0.f ? x1 : SLOPE * x1;
                float x2 = acc2[i] + bb2; x2 = x2 > 0.f ? x2 : SLOPE * x2;
                out[(size_t)row * DD + j0 + m] = x1 + x2;
            }
        }
    }
}

// ---------------------------------------------------------------------------
// Fused fallback (r7 verbatim, used when ws can't hold Hf): 84-85 us proven.
// ---------------------------------------------------------------------------
__global__ __launch_bounds__(256, 4) void bucket_fused(
    const unsigned short* __restrict__ Ebf, const int* __restrict__ gtail,
    const unsigned int* __restrict__ stag, const int* __restrict__ ovf_cnt,
    const int2* __restrict__ ovf,
    const unsigned short* __restrict__ W1b, const unsigned short* __restrict__ W2b,
    const float* __restrict__ b1, const float* __restrict__ b2,
    float* __restrict__ out)
{
    __shared__ unsigned short sorted[BCAP];
    __shared__ unsigned short Hs[64][HP];
    __shared__ int cnt[64], off[65], pos[64];
    __shared__ int s_novf;

    const int b = blockIdx.x;
    const int tid = threadIdx.x;
    int len = gtail[b]; len = len < BCAP ? len : BCAP;
    const unsigned int* seg = stag + (size_t)b * BCAP;

    if (tid == 0) { int t = *ovf_cnt; s_novf = t < OVCAP ? t : OVCAP; }
    if (tid < 64) cnt[tid] = 0;
    __syncthreads();
    for (int i = tid; i < len; i += 256)
        atomicAdd(&cnt[(seg[i] >> 16) & 63], 1);
    __syncthreads();
    if (tid < 64) {
        int cv = cnt[tid];
        int incl = cv;
        #pragma unroll
        for (int d = 1; d < 64; d <<= 1) {
            int t2 = __shfl_up(incl, d);
            if (tid >= d) incl += t2;
        }
        off[tid] = incl - cv;
        pos[tid] = incl - cv;
        if (tid == 63) off[64] = incl;
    }
    __syncthreads();
    for (int i = tid; i < len; i += 256) {
        unsigned int r = seg[i];
        int p = atomicAdd(&pos[(r >> 16) & 63], 1);
        sorted[p] = (unsigned short)(r & 0xffffu);
    }
    __syncthreads();
    const int novf = s_novf;

    const int g = tid >> 4;
    const int c = tid & 15;
    const uint4* E4 = (const uint4*)Ebf;
    for (int p4 = 0; p4 < 4; ++p4) {
        int nl = p4 * 16 + g;
        int v = b * 64 + nl;
        if (v >= NN) continue;
        float acc[8] = {};
        int i = off[nl], e1 = off[nl + 1];
        uint4 r[8];
        for (; i + 8 <= e1; i += 8) {
            #pragma unroll
            for (int k = 0; k < 8; ++k)
                r[k] = E4[(size_t)sorted[i + k] * 16 + c];
            __builtin_amdgcn_sched_barrier(0);
            #pragma unroll
            for (int k = 0; k < 8; ++k) addrow(acc, r[k]);
        }
        for (; i + 2 <= e1; i += 2) {
            uint4 r0 = E4[(size_t)sorted[i]     * 16 + c];
            uint4 r1 = E4[(size_t)sorted[i + 1] * 16 + c];
            addrow(acc, r0); addrow(acc, r1);
        }
        if (i < e1) addrow(acc, E4[(size_t)sorted[i] * 16 + c]);
        if (novf > 0) {
            for (int k = 0; k < novf; ++k) {
                int2 e = ovf[k];
                if (e.y == v) addrow(acc, E4[(size_t)e.x * 16 + c]);
            }
        }
        uint4 o;
        o.x = pack2(acc[0], acc[1]); o.y = pack2(acc[2], acc[3]);
        o.z = pack2(acc[4], acc[5]); o.w = pack2(acc[6], acc[7]);
        *(uint4*)&Hs[nl][c * 8] = o;
    }
    __syncthreads();

    const int wave = tid >> 6;
    const int lane = tid & 63;
    const int v0 = b * 64 + wave * 16;
    if (v0 >= NN) return;
    const int m = lane & 15;
    const int quad = lane >> 4;

    bf16x8 aH[4], aE[4];
    const unsigned short* hrow = &Hs[wave * 16 + m][quad * 8];
    const unsigned short* erow = Ebf + (size_t)(v0 + m) * DD + quad * 8;
    #pragma unroll
    for (int ks = 0; ks < 4; ++ks) {
        bf16x8 h8 = *(const bf16x8*)(hrow + ks * 32);
        bf16x8 e8 = *(const bf16x8*)(erow + ks * 32);
        aH[ks] = h8;
        bf16x8 eh;
        #pragma unroll
        for (int j = 0; j < 8; ++j)
            eh[j] = (short)rnebf(sbf(h8[j]) * sbf(e8[j]));
        aE[ks] = eh;
    }
    #pragma unroll
    for (int jt = 0; jt < 8; ++jt) {
        const int j0 = jt * 16;
        const unsigned short* w1r = W1b + (size_t)(j0 + m) * DD + quad * 8;
        const unsigned short* w2r = W2b + (size_t)(j0 + m) * DD + quad * 8;
        f32x4 acc1 = {0.f, 0.f, 0.f, 0.f}, acc2 = {0.f, 0.f, 0.f, 0.f};
        #pragma unroll
        for (int ks = 0; ks < 4; ++ks) {
            bf16x8 bw1 = *(const bf16x8*)(w1r + ks * 32);
            bf16x8 bw2 = *(const bf16x8*)(w2r + ks * 32);
            acc1 = __builtin_amdgcn_mfma_f32_16x16x32_bf16(aH[ks], bw1, acc1, 0, 0, 0);
            acc2 = __builtin_amdgcn_mfma_f32_16x16x32_bf16(aE[ks], bw2, acc2, 0, 0, 0);
        }
        const float bb1 = b1[j0 + m], bb2 = b2[j0 + m];
        #pragma unroll
        for (int i = 0; i < 4; ++i) {
            int row = v0 + quad * 4 + i;
            if (row < NN) {
                float x1 = acc1[i] + bb1; x1 = x1 > 0.f ? x1 : SLOPE * x1;
                float x2 = acc2[i] + bb2; x2 = x2 > 0.f ? x2 : SLOPE * x2;
                out[(size_t)row * DD + j0 + m] = x1 + x2;
            }
        }
    }
}

// ============== minimal fallback (ws too small): fp32 atomics ==============
__global__ __launch_bounds__(256) void scatter_add(
    const float* __restrict__ E, const int* __restrict__ src,
    const int* __restrict__ dst, float* __restrict__ H, int n_edges)
{
    int t = blockIdx.x * 256 + threadIdx.x;
    int e = t >> 5;
    if (e >= n_edges) return;
    int c = t & 31;
    float4 a = ((const float4*)E)[(size_t)src[e] * 32 + c];
    float* hp = H + (size_t)dst[e] * DD + c * 4;
    atomicAdd(hp + 0, a.x); atomicAdd(hp + 1, a.y);
    atomicAdd(hp + 2, a.z); atomicAdd(hp + 3, a.w);
}

__global__ __launch_bounds__(256) void fused_mlp(
    const float* __restrict__ E, const float* __restrict__ H,
    const float* __restrict__ W1, const float* __restrict__ b1,
    const float* __restrict__ W2, const float* __restrict__ b2,
    float* __restrict__ out)
{
    __shared__ float Hsf[32][DD];
    __shared__ float EHs[32][DD];
    __shared__ float W1s[DD][20];
    __shared__ float W2s[DD][20];
    const int tid = threadIdx.x;
    const int v0 = blockIdx.x * 32;
    const int nvalid = min(32, NN - v0);
    for (int i = 0; i < 4; ++i) {
        int f = tid + 256 * i;
        int n = f >> 5, c = f & 31;
        float4 h = make_float4(0.f, 0.f, 0.f, 0.f);
        float4 eh = h;
        if (n < nvalid) {
            h = ((const float4*)H)[(size_t)(v0 + n) * 32 + c];
            float4 e4 = ((const float4*)E)[(size_t)(v0 + n) * 32 + c];
            eh = make_float4(e4.x * h.x, e4.y * h.y, e4.z * h.z, e4.w * h.w);
        }
        *((float4*)&Hsf[n][c * 4]) = h;
        *((float4*)&EHs[n][c * 4]) = eh;
    }
    const int jg = tid & 63;
    const int n0 = (tid >> 6) * 8;
    float acc1a[8] = {}, acc1b[8] = {}, acc2a[8] = {}, acc2b[8] = {};
    for (int t8 = 0; t8 < 8; ++t8) {
        const int k0 = t8 * 16;
        __syncthreads();
        for (int i = 0; i < 8; ++i) {
            int f = tid + 256 * i;
            int j = f >> 4, kk = f & 15;
            W1s[j][kk] = W1[j * DD + k0 + kk];
            W2s[j][kk] = W2[j * DD + k0 + kk];
        }
        __syncthreads();
        for (int c = 0; c < 4; ++c) {
            float4 w1a = *((const float4*)&W1s[jg][c * 4]);
            float4 w1b = *((const float4*)&W1s[jg + 64][c * 4]);
            float4 w2a = *((const float4*)&W2s[jg][c * 4]);
            float4 w2b = *((const float4*)&W2s[jg + 64][c * 4]);
            const int kk = k0 + c * 4;
            for (int n = 0; n < 8; ++n) {
                float4 h = *((const float4*)&Hsf[n0 + n][kk]);
                float4 eh = *((const float4*)&EHs[n0 + n][kk]);
                acc1a[n] += h.x * w1a.x + h.y * w1a.y + h.z * w1a.z + h.w * w1a.w;
                acc1b[n] += h.x * w1b.x + h.y * w1b.y + h.z * w1b.z + h.w * w1b.w;
                acc2a[n] += eh.x * w2a.x + eh.y * w2a.y + eh.z * w2a.z + eh.w * w2a.w;
                acc2b[n] += eh.x * w2b.x + eh.y * w2b.y + eh.z * w2b.z + eh.w * w2b.w;
            }
        }
    }
    const float b1a = b1[jg], b1b = b1[jg + 64];
    const float b2a = b2[jg], b2b = b2[jg + 64];
    for (int n = 0; n < 8; ++n) {
        if (n0 + n < nvalid) {
            const int v = v0 + n0 + n;
            float x1 = acc1a[n] + b1a; x1 = x1 > 0.f ? x1 : SLOPE * x1;
            float x2 = acc2a[n] + b2a; x2 = x2 > 0.f ? x2 : SLOPE * x2;
            out[(size_t)v * DD + jg] = x1 + x2;
            float y1 = acc1b[n] + b1b; y1 = y1 > 0.f ? y1 : SLOPE * y1;
            float y2 = acc2b[n] + b2b; y2 = y2 > 0.f ? y2 : SLOPE * y2;
            out[(size_t)v * DD + jg + 64] = y1 + y2;
        }
    }
}
// ===========================================================================

extern "C" void kernel_launch(void* const* d_in, const int* in_sizes, int n_in,
                              void* d_out, int out_size, void* d_ws, size_t ws_size,
                              hipStream_t stream)
{
    const float* E  = (const float*)d_in[0];
    const float* W1 = (const float*)d_in[1];
    const float* b1 = (const float*)d_in[2];
    const float* W2 = (const float*)d_in[3];
    const float* b2 = (const float*)d_in[4];
    const int* src  = (const int*)d_in[5];
    const int* dst  = (const int*)d_in[6];
    float* out = (float*)d_out;
    const int n_edges = in_sizes[5];

    char* ws = (char*)d_ws;
    auto al = [](size_t x) { return (x + 255) & ~(size_t)255; };

    const int nch1 = (n_edges + ECH1 - 1) / ECH1;

    // counters: gtail1[NSB] | ovf_cnt[1] | gtail[NB]
    const size_t ctr_ints  = NSB + 1 + NB;
    const size_t off_ovf   = al(ctr_ints * 4);
    const size_t off_stag1 = al(off_ovf + (size_t)OVCAP * 8);
    const size_t off_stag  = al(off_stag1 + (size_t)NSB * SCAP * 4);
    const size_t off_Ebf   = al(off_stag + (size_t)NB * BCAP * 4);
    const size_t off_W1b   = al(off_Ebf + (size_t)NN * DD * 2);
    const size_t off_W2b   = al(off_W1b + (size_t)DD * DD * 2);
    const size_t need_bf   = off_W2b + (size_t)DD * DD * 2;     // ~27 MB
    const size_t off_Hf    = al(need_bf);
    const size_t need_split = off_Hf + (size_t)NN * DD * 4;     // ~53 MB

    if (ws_size >= need_bf) {
        int*  gtail1  = (int*)ws;
        int*  ovf_cnt = gtail1 + NSB;
        int*  gtail   = gtail1 + NSB + 1;
        int2* ovf     = (int2*)(ws + off_ovf);
        unsigned int*   stag1 = (unsigned int*)(ws + off_stag1);
        unsigned int*   stag  = (unsigned int*)(ws + off_stag);
        unsigned short* Ebf   = (unsigned short*)(ws + off_Ebf);
        unsigned short* W1b   = (unsigned short*)(ws + off_W1b);
        unsigned short* W2b   = (unsigned short*)(ws + off_W2b);

        const int NCV  = NN * DD / 8 + 2 * (DD * DD / 8);
        const int ncvb = (NCV + 511) / 512;

        hipMemsetAsync(ws, 0, ctr_ints * 4, stream);
        scatter_convert<<<nch1 + ncvb, 512, 0, stream>>>(
            E, W1, W2, src, dst, Ebf, W1b, W2b,
            gtail1, stag1, ovf_cnt, ovf, n_edges, nch1);
        rebin<<<NSB * RS, 256, 0, stream>>>(
            gtail1, stag1, gtail, stag, ovf_cnt, ovf);

        if (ws_size >= need_split) {
            float* Hf = (float*)(ws + off_Hf);
            bucket_gather<<<NB * 2, 256, 0, stream>>>(
                Ebf, gtail, stag, ovf_cnt, ovf, Hf);
            bucket_gemm<<<NB, 256, 0, stream>>>(
                Hf, Ebf, W1b, W2b, b1, b2, out);
        } else {
            bucket_fused<<<NB, 256, 0, stream>>>(
                Ebf, gtail, stag, ovf_cnt, ovf, W1b, W2b, b1, b2, out);
        }
        return;
    }

    // fallback: fp32 atomics into H (= ws if it fits, else out), then fused MLP
    const size_t hbytes = (size_t)NN * DD * sizeof(float);
    float* H = (ws_size >= hbytes) ? (float*)ws : out;
    hipMemsetAsync(H, 0, hbytes, stream);
    scatter_add<<<((n_edges * 32) + 255) / 256, 256, 0, stream>>>(
        E, src, dst, H, n_edges);
    fused_mlp<<<(NN + 31) / 32, 256, 0, stream>>>(E, H, W1, b1, W2, b2, out);
}